// Round 18
// baseline (273.557 us; speedup 1.0000x reference)
//
#include <hip/hip_runtime.h>
#include <stdint.h>
#include <stddef.h>

typedef _Float16 f16;
typedef _Float16 f16x8 __attribute__((ext_vector_type(8)));
typedef _Float16 f16x4 __attribute__((ext_vector_type(4)));
typedef float f32x4 __attribute__((ext_vector_type(4)));

__device__ __forceinline__ void gload16(const void* g, void* l) {
    auto gp = (const __attribute__((address_space(1))) uint32_t*)(uintptr_t)g;
    auto lp = (__attribute__((address_space(3))) uint32_t*)(uintptr_t)l;
    __builtin_amdgcn_global_load_lds(gp, lp, 16, 0, 0);
}

__device__ __forceinline__ f16x4 cvt4(f32x4 v) {
    return f16x4{ (f16)v[0], (f16)v[1], (f16)v[2], (f16)v[3] };
}

// ---------------- prep: weight f32 -> f16 conversions only --------------------
__global__ __launch_bounds__(256) void prep_k(const float* __restrict__ wqkv,
                                              const float* __restrict__ wout,
                                              f16* __restrict__ wqb,
                                              f16* __restrict__ wob) {
    int tid = blockIdx.x * blockDim.x + threadIdx.x;
    int stride = gridDim.x * blockDim.x;
    for (int i = tid; i < 196608; i += stride) {
        float4 v = ((const float4*)wqkv)[i];
        *(f16x4*)(wqb + (size_t)i * 4) = f16x4{ (f16)v.x, (f16)v.y, (f16)v.z, (f16)v.w };
    }
    for (int i = tid; i < 65536; i += stride) {
        float4 v = ((const float4*)wout)[i];
        *(f16x4*)(wob + (size_t)i * 4) = f16x4{ (f16)v.x, (f16)v.y, (f16)v.z, (f16)v.w };
    }
}

#define W0  asm volatile("s_waitcnt vmcnt(0)" ::: "memory")
#define BAR __builtin_amdgcn_s_barrier()

// ============ ENGINE A3: g16 = merged QKV, A direct-from-x (f32) ==============
// 128x128 tile, BK=64, 4 waves, dbuf 64KB LDS, 2 blocks/CU (r6-verified core).
// A staged via registers: 8x float4 loads of x (pre-swizzled source, byte
// offsets 2x the f16 layout) -> cvt -> ds_write_b128 to the SAME linear LDS
// slots gload16 produced; B (f16 weights) stays gload16.  Eliminates the
// 96MB xb conversion round-trip (prep's x pass).

#define LOADX do {                                                              \
    xr[0] = *(const float4*)(Xb + kb2 + sEX);                                   \
    xr[1] = *(const float4*)(Xb + kb2 + sEX + 16);                              \
    xr[2] = *(const float4*)(Xb + kb2 + sOX + 65536);                           \
    xr[3] = *(const float4*)(Xb + kb2 + sOX + 65536 + 16);                      \
    xr[4] = *(const float4*)(Xb + kb2 + sEX + 131072);                          \
    xr[5] = *(const float4*)(Xb + kb2 + sEX + 131072 + 16);                     \
    xr[6] = *(const float4*)(Xb + kb2 + sOX + 196608);                          \
    xr[7] = *(const float4*)(Xb + kb2 + sOX + 196608 + 16);                     \
    kb2 += 256;                                                                 \
} while (0)

#define CVTW(NB) do {                                                           \
    _Pragma("unroll") for (int c = 0; c < 4; ++c) {                             \
        f16x8 v;                                                                \
        v[0] = (f16)xr[c*2].x; v[1] = (f16)xr[c*2].y;                           \
        v[2] = (f16)xr[c*2].z; v[3] = (f16)xr[c*2].w;                           \
        v[4] = (f16)xr[c*2+1].x; v[5] = (f16)xr[c*2+1].y;                       \
        v[6] = (f16)xr[c*2+1].z; v[7] = (f16)xr[c*2+1].w;                       \
        *(f16x8*)&ldsA[NB][(c * 32 + wid * 8) * 64 + lane * 8] = v;             \
    }                                                                           \
} while (0)

#define BSTG(NB) do {                                                           \
    gload16(Bb + kb + sE,          &ldsB[NB][( 0 + wid*8)*64]);                 \
    gload16(Bb + kb + sO + 32768,  &ldsB[NB][(32 + wid*8)*64]);                 \
    gload16(Bb + kb + sE + 65536,  &ldsB[NB][(64 + wid*8)*64]);                 \
    gload16(Bb + kb + sO + 98304,  &ldsB[NB][(96 + wid*8)*64]);                 \
    kb += 128;                                                                  \
} while (0)

#define A_RD(SET, BUF) do {                                                     \
    _Pragma("unroll") for (int mi = 0; mi < 4; ++mi)                            \
    _Pragma("unroll") for (int kk = 0; kk < 2; ++kk)                            \
        aF##SET[mi][kk] = *(const f16x8*)(&ldsA[BUF][0] + aoff[mi][kk]);        \
    _Pragma("unroll") for (int ni = 0; ni < 4; ++ni)                            \
    _Pragma("unroll") for (int kk = 0; kk < 2; ++kk)                            \
        bF##SET[ni][kk] = *(const f16x8*)(&ldsB[BUF][0] + boff[ni][kk]);        \
} while (0)

#define A_MM(SET, KK, ML, MH_) do {                                             \
    __builtin_amdgcn_s_setprio(1);                                              \
    if (qk) {                                                                   \
        _Pragma("unroll") for (int mi = ML; mi < MH_; ++mi)                     \
        _Pragma("unroll") for (int ni = 0; ni < 4; ++ni)                        \
            acc[mi][ni] = __builtin_amdgcn_mfma_f32_16x16x32_f16(               \
                aF##SET[mi][KK], bF##SET[ni][KK], acc[mi][ni], 0, 0, 0);        \
    } else {                                                                    \
        _Pragma("unroll") for (int mi = ML; mi < MH_; ++mi)                     \
        _Pragma("unroll") for (int ni = 0; ni < 4; ++ni)                        \
            acc[mi][ni] = __builtin_amdgcn_mfma_f32_16x16x32_f16(               \
                bF##SET[ni][KK], aF##SET[mi][KK], acc[mi][ni], 0, 0, 0);        \
    }                                                                           \
    __builtin_amdgcn_s_setprio(0);                                              \
} while (0)

#define A_MM3(SET)   do { A_MM(SET, 0, 0, 2); A_MM(SET, 0, 2, 4); A_MM(SET, 1, 0, 2); } while (0)
#define A_MMLAST(SET) A_MM(SET, 1, 2, 4)

#define A_TILE(CUR, NXT, NB, STG, FINAL) do {                                   \
    if (STG) { LOADX; BSTG(NB); }                                               \
    A_MM3(CUR);                                                                 \
    if (!FINAL) {                                                               \
        CVTW(NB);                                                               \
        W0;                                                                     \
        asm volatile("s_waitcnt lgkmcnt(0)" ::: "memory");                      \
        BAR;                                                                    \
        A_RD(NXT, NB);                                                          \
    }                                                                           \
    A_MMLAST(CUR);                                                              \
} while (0)

__global__ __launch_bounds__(256, 2) void g16_k(const float* __restrict__ X0,
                                                const f16* __restrict__ B0,
                                                f16* __restrict__ Qd,
                                                f16* __restrict__ Kd,
                                                f16* __restrict__ Vd) {
    __shared__ f16 ldsA[2][8192];
    __shared__ f16 ldsB[2][8192];

    const int tid = threadIdx.x;
    const int lane = tid & 63;
    const int wid = tid >> 6;
    const int wr = wid >> 1;
    const int wc = wid & 1;

    const int bid = blockIdx.x;
    const bool qk = bid < 2048;
    int tm, tn;
    if (qk) {
        int swz = (bid & 7) * 256 + (bid >> 3);       // 2048 QK blocks
        tm = (swz >> 3) * 128; tn = (swz & 7) * 128;
    } else {
        int b2 = bid - 2048;
        int swz = (b2 & 7) * 128 + (b2 >> 3);         // 1024 V blocks
        tm = (swz >> 2) * 128; tn = (swz & 3) * 128 + 1024;
    }

    const char* Xb = (const char*)(X0 + (size_t)tm * 512);
    const char* Bb = (const char*)(B0 + (size_t)tn * 512);

    const int u = tid >> 3;
    const int colE = ((tid & 7) ^ ((u & 7) ^ (u >> 3))) * 16;
    const int sE = u * 1024 + colE;       // f16-byte staging offset (B)
    const int sO = sE ^ 64;
    const int sEX = u * 2048 + colE * 2;  // f32-byte staging offset (A from x)
    const int sOX = sEX ^ 128;
    int kb = 0, kb2 = 0;
    float4 xr[8];

    int aoff[4][2], boff[4][2];
#pragma unroll
    for (int mi = 0; mi < 4; ++mi) {
        int r = qk ? ((lane & 15) * 8 + wr * 4 + mi)
                   : (wr * 64 + mi * 16 + (lane & 15));
#pragma unroll
        for (int kk = 0; kk < 2; ++kk) {
            int c8 = (lane >> 4) + kk * 4;
            aoff[mi][kk] = r * 64 + (c8 ^ ((r & 7) ^ ((r >> 3) & 7))) * 8;
        }
    }
#pragma unroll
    for (int ni = 0; ni < 4; ++ni) {
        int r = wc * 64 + ni * 16 + (lane & 15);
#pragma unroll
        for (int kk = 0; kk < 2; ++kk) {
            int c8 = (lane >> 4) + kk * 4;
            boff[ni][kk] = r * 64 + (c8 ^ ((r & 7) ^ ((r >> 3) & 7))) * 8;
        }
    }

    f32x4 acc[4][4] = {};
    f16x8 aF0[4][2], bF0[4][2], aF1[4][2], bF1[4][2];

    // prologue: load+stage tile 0, convert, drain, read set0
    LOADX;
    BSTG(0);
    CVTW(0);
    W0;
    asm volatile("s_waitcnt lgkmcnt(0)" ::: "memory");
    BAR;
    A_RD(0, 0);

#pragma unroll 1
    for (int i = 0; i < 3; ++i) {
        A_TILE(0, 1, 1, true, false);
        A_TILE(1, 0, 0, true, false);
    }
    A_TILE(0, 1, 1, true, false);   // t6
    A_TILE(1, 1, 1, false, true);   // t7

    if (qk) {
        const int b = tm >> 12;
        const int lt = (tm & 4095) >> 3;
        f16* dst = (tn < 512) ? Qd : Kd;
        const int cb = (tn & 511) + wc * 64;
        const int lh0 = lt + (lane >> 4) * 4;
#pragma unroll
        for (int mi = 0; mi < 4; ++mi) {
            int h = wr * 4 + mi;
#pragma unroll
            for (int ni = 0; ni < 4; ++ni) {
                int c = cb + ni * 16 + (lane & 15);
                *(f16x4*)(dst + ((size_t)((b * 8 + h) * 512 + c)) * 512 + lh0) =
                    cvt4(acc[mi][ni]);
            }
        }
    } else {
        f16* dst = Vd;
#pragma unroll
        for (int mi = 0; mi < 4; ++mi) {
            int t = tm + wr * 64 + mi * 16 + (lane & 15);
            int b = t >> 12, l = t & 4095;
            int h = l & 7, lh = l >> 3;
#pragma unroll
            for (int ni = 0; ni < 4; ++ni) {
                int d0 = (tn - 1024) + wc * 64 + ni * 16 + (lane >> 4) * 4;
                *(f16x4*)(dst + ((size_t)((b * 8 + h) * 512 + lh)) * 512 + d0) =
                    cvt4(acc[mi][ni]);
            }
        }
    }
}

// ======= ENGINE F: fused attention (r17 verbatim) =============================
#define F_STAGE(B) do {                                                         \
    gload16(Qt + kb + soff,           &L[65536 + (B)*8192 + ( 0 + wid*8)*64]);  \
    gload16(Qt + kb + soff + 65536,   &L[65536 + (B)*8192 + (64 + wid*8)*64]);  \
    gload16(Kt + kb + soff,           &L[(B)*32768 + (  0 + wid*8)*64]);        \
    gload16(Kt + kb + soff + 65536,   &L[(B)*32768 + ( 64 + wid*8)*64]);        \
    gload16(Kt + kb + soff + 131072,  &L[(B)*32768 + (128 + wid*8)*64]);        \
    gload16(Kt + kb + soff + 196608,  &L[(B)*32768 + (192 + wid*8)*64]);        \
    gload16(Kt + kb + soff + 262144,  &L[(B)*32768 + (256 + wid*8)*64]);        \
    gload16(Kt + kb + soff + 327680,  &L[(B)*32768 + (320 + wid*8)*64]);        \
    gload16(Kt + kb + soff + 393216,  &L[(B)*32768 + (384 + wid*8)*64]);        \
    gload16(Kt + kb + soff + 458752,  &L[(B)*32768 + (448 + wid*8)*64]);        \
    kb += 128;                                                                  \
} while (0)

#define F_RD(KK, B) do {                                                        \
    _Pragma("unroll") for (int ni = 0; ni < 4; ++ni)                            \
        bF[ni] = *(const f16x8*)(&L[(B)*32768] + boff[ni][KK]);                 \
    _Pragma("unroll") for (int mi = 0; mi < 8; ++mi)                            \
        aF[mi] = *(const f16x8*)(&L[65536 + (B)*8192] + aoff[mi][KK]);          \
} while (0)

#define F_MM do {                                                               \
    __builtin_amdgcn_s_setprio(1);                                              \
    _Pragma("unroll") for (int mi = 0; mi < 8; ++mi)                            \
    _Pragma("unroll") for (int ni = 0; ni < 4; ++ni)                            \
        acc[mi][ni] = __builtin_amdgcn_mfma_f32_16x16x32_f16(                   \
            aF[mi], bF[ni], acc[mi][ni], 0, 0, 0);                              \
    __builtin_amdgcn_s_setprio(0);                                              \
} while (0)

__global__ __launch_bounds__(512) void attn_k(const f16* __restrict__ Qb,
                                              const f16* __restrict__ Kb,
                                              const f16* __restrict__ Vb,
                                              f16* __restrict__ yb) {
    __shared__ __align__(16) f16 L[81920];   // 160 KB exactly

    const int tid = threadIdx.x;
    const int lane = tid & 63;
    const int wid = tid >> 6;
    const int g = lane >> 4;
    const int li = lane & 15;

    const int bid = blockIdx.x;
    const int swz = (bid & 7) * 32 + (bid >> 3);
    const int bh = swz >> 2, ct = swz & 3;
    const int b = bh >> 3, h = bh & 7;

    const char* Qt = (const char*)(Qb + (size_t)bh * 262144 + (size_t)ct * 128 * 512);
    const char* Kt = (const char*)(Kb + (size_t)bh * 262144);
    const char* Vt = (const char*)(Vb + (size_t)bh * 262144);

    const int soff = (tid >> 3) * 1024 +
                     ((((lane & 7) ^ (lane >> 3) ^ wid) & 7) * 16);
    int kb = 0;

    int aoff[8][2], boff[4][2];
#pragma unroll
    for (int mi = 0; mi < 8; ++mi) {
        int r = mi * 16 + li;
        int s3 = (r & 7) ^ ((r >> 3) & 7);
#pragma unroll
        for (int kk = 0; kk < 2; ++kk)
            aoff[mi][kk] = r * 64 + (((g + kk * 4) ^ s3)) * 8;
    }
#pragma unroll
    for (int ni = 0; ni < 4; ++ni) {
        int r = wid * 64 + ni * 16 + li;
        int s3 = (r & 7) ^ ((r >> 3) & 7);
#pragma unroll
        for (int kk = 0; kk < 2; ++kk)
            boff[ni][kk] = r * 64 + (((g + kk * 4) ^ s3)) * 8;
    }

    f32x4 acc[8][4] = {};
    f16x8 aF[8], bF[4];

    F_STAGE(0);
#pragma unroll 1
    for (int t = 0; t < 8; ++t) {
        const int cb = t & 1;
        if (t < 7) {
            F_STAGE(cb ^ 1);
            asm volatile("s_waitcnt vmcnt(10)" ::: "memory");
        } else {
            W0;
        }
        BAR;
        F_RD(0, cb);
        F_MM;
        F_RD(1, cb);
        F_MM;
        BAR;
    }

    const int voff = (lane >> 2) * 1024 +
                     ((((lane & 3) ^ ((lane >> 2) & 3) ^ g) & 3) * 16);
    f16x8 vr[4];
#pragma unroll
    for (int i = 0; i < 4; ++i)
        vr[i] = *(const f16x8*)(Vt + (size_t)((wid * 4 + i) * 16) * 1024 + voff);

    float* red  = (float*)&L[65536];
    float* redg = (float*)&L[65536 + 2048];

#pragma unroll
    for (int mi = 0; mi < 8; ++mi)
#pragma unroll
        for (int ni = 0; ni < 4; ++ni) acc[mi][ni] *= 0.125f;

#pragma unroll
    for (int mi = 0; mi < 8; ++mi)
#pragma unroll
        for (int j = 0; j < 4; ++j) {
            float v = fmaxf(fmaxf(acc[mi][0][j], acc[mi][1][j]),
                            fmaxf(acc[mi][2][j], acc[mi][3][j]));
#pragma unroll
            for (int off = 1; off < 16; off <<= 1) v = fmaxf(v, __shfl_xor(v, off, 64));
            if (li == 0) red[wid * 128 + mi * 16 + g * 4 + j] = v;
        }
    BAR;
    if (tid < 128) {
        float m = red[tid];
#pragma unroll
        for (int w = 1; w < 8; ++w) m = fmaxf(m, red[w * 128 + tid]);
        redg[tid] = m;
    }
    BAR;

#pragma unroll
    for (int mi = 0; mi < 8; ++mi)
#pragma unroll
        for (int j = 0; j < 4; ++j) {
            float mg = redg[mi * 16 + g * 4 + j];
            float s = 0.f;
#pragma unroll
            for (int ni = 0; ni < 4; ++ni) {
                float e = __expf(acc[mi][ni][j] - mg);
                acc[mi][ni][j] = e;
                s += e;
            }
#pragma unroll
            for (int off = 1; off < 16; off <<= 1) s += __shfl_xor(s, off, 64);
            if (li == 0) red[wid * 128 + mi * 16 + g * 4 + j] = s;
        }
    BAR;
    if (tid < 128) {
        float s = red[tid];
#pragma unroll
        for (int w = 1; w < 8; ++w) s += red[w * 128 + tid];
        redg[tid] = 1.0f / s;
    }
    BAR;

#pragma unroll
    for (int mi = 0; mi < 8; ++mi)
#pragma unroll
        for (int j = 0; j < 4; ++j) {
            int c = mi * 16 + g * 4 + j;
            int s3c = (c & 7) ^ ((c >> 3) & 7);
            float is = redg[c];
#pragma unroll
            for (int ni = 0; ni < 4; ++ni) {
                int dch = wid * 8 + ni * 2 + (li >> 3);
                L[c * 512 + ((dch ^ s3c) << 3) + (li & 7)] =
                    (f16)(acc[mi][ni][j] * is);
            }
        }
    BAR;

#pragma unroll
    for (int mi = 0; mi < 8; ++mi)
#pragma unroll
        for (int ni = 0; ni < 4; ++ni) acc[mi][ni] = f32x4{0.f, 0.f, 0.f, 0.f};

#pragma unroll 1
    for (int dt = 0; dt < 16; ++dt) {
#pragma unroll
        for (int i = 0; i < 4; ++i)
            *(f16x8*)&L[65536 + (wid * 4 + i) * 512 + lane * 8] = vr[i];
        if (dt < 15) {
#pragma unroll
            for (int i = 0; i < 4; ++i)
                vr[i] = *(const f16x8*)(Vt + (size_t)((wid * 4 + i) * 16) * 1024 +
                                        (dt + 1) * 64 + voff);
        }
        asm volatile("s_waitcnt lgkmcnt(0)" ::: "memory");
        BAR;
        f16x8 aP[8], bV[4];
#pragma unroll
        for (int mi = 0; mi < 8; ++mi) {
            int c = mi * 16 + li;
            int s3c = (c & 7) ^ ((c >> 3) & 7);
            aP[mi] = *(const f16x8*)&L[c * 512 + (((dt * 4 + g) ^ s3c) << 3)];
        }
#pragma unroll
        for (int ni = 0; ni < 4; ++ni) {
            int lr = wid * 64 + ni * 16 + li;
            int s2 = (lr & 3) ^ ((lr >> 2) & 3);
            bV[ni] = *(const f16x8*)&L[65536 + lr * 32 + ((g ^ s2) & 3) * 8];
        }
        __builtin_amdgcn_s_setprio(1);
#pragma unroll
        for (int mi = 0; mi < 8; ++mi)
#pragma unroll
            for (int ni = 0; ni < 4; ++ni)
                acc[mi][ni] = __builtin_amdgcn_mfma_f32_16x16x32_f16(
                    aP[mi], bV[ni], acc[mi][ni], 0, 0, 0);
        __builtin_amdgcn_s_setprio(0);
        BAR;
    }

#pragma unroll
    for (int mi = 0; mi < 8; ++mi) {
        int c0 = ct * 128 + mi * 16 + g * 4;
#pragma unroll
        for (int ni = 0; ni < 4; ++ni) {
            int l = wid * 64 + ni * 16 + li;
            size_t tok = (size_t)b * 4096 + (size_t)l * 8 + h;
            *(f16x4*)(yb + tok * 512 + c0) = cvt4(acc[mi][ni]);
        }
    }
}

// ======================= ENGINE B: out_k (r17 verbatim) =======================
#define B_STAGE(NB) do {                                                        \
    gload16(At + soff,          &ldsA2[NB][(  0 + wid*8)*64]);                  \
    gload16(At + soff + 65536,  &ldsA2[NB][( 64 + wid*8)*64]);                  \
    gload16(At + soff + 131072, &ldsA2[NB][(128 + wid*8)*64]);                  \
    gload16(At + soff + 196608, &ldsA2[NB][(192 + wid*8)*64]);                  \
    gload16(Bt + soff,          &ldsB2[NB][(  0 + wid*8)*64]);                  \
    gload16(Bt + soff + 65536,  &ldsB2[NB][( 64 + wid*8)*64]);                  \
    gload16(Bt + soff + 131072, &ldsB2[NB][(128 + wid*8)*64]);                  \
    gload16(Bt + soff + 196608, &ldsB2[NB][(192 + wid*8)*64]);                  \
    At += 128; Bt += 128;                                                       \
} while (0)

#define B_RD12(KK, BUF) do {                                                    \
    _Pragma("unroll") for (int ni = 0; ni < 4; ++ni)                            \
        bF[ni] = *(const f16x8*)(&ldsB2[BUF][0] + boff[ni][KK]);                \
    _Pragma("unroll") for (int mi = 0; mi < 8; ++mi)                            \
        aF[mi] = *(const f16x8*)(&ldsA2[BUF][0] + aoff[mi][KK]);                \
} while (0)

#define B_MM32 do {                                                             \
    __builtin_amdgcn_s_setprio(1);                                              \
    _Pragma("unroll") for (int mi = 0; mi < 8; ++mi)                            \
    _Pragma("unroll") for (int ni = 0; ni < 4; ++ni)                            \
        acc[mi][ni] = __builtin_amdgcn_mfma_f32_16x16x32_f16(                   \
            bF[ni], aF[mi], acc[mi][ni], 0, 0, 0);                              \
    __builtin_amdgcn_s_setprio(0);                                              \
} while (0)

#define B_TILE(CB, NB, STG, FINAL) do {                                         \
    B_RD12(0, CB);                                                              \
    if (STG) B_STAGE(NB);                                                       \
    B_MM32;                                                                     \
    B_RD12(1, CB);                                                              \
    B_MM32;                                                                     \
    if (!FINAL) { W0; BAR; }                                                    \
} while (0)

__global__ __launch_bounds__(512) void out_k(const f16* __restrict__ A0,
                                             const f16* __restrict__ B0,
                                             float* __restrict__ O,
                                             const float* __restrict__ bias) {
    __shared__ f16 ldsA2[2][16384];
    __shared__ f16 ldsB2[2][16384];

    const int tid = threadIdx.x;
    const int lane = tid & 63;
    const int wid = tid >> 6;
    const int wr = wid >> 2;
    const int wc = wid & 3;

    const int bid = blockIdx.x;
    int swz = (bid & 7) * 32 + (bid >> 3);   // 256 blocks, bijective
    int tm = (swz >> 1) * 256, tn = (swz & 1) * 256;

    const char* At = (const char*)(A0 + (size_t)tm * 512);
    const char* Bt = (const char*)(B0 + (size_t)tn * 512);

    const int soff = wid * 8192 + (lane >> 3) * 1024 +
                     ((((lane & 7) ^ (lane >> 3) ^ wid) & 7) * 16);

    int aoff[8][2], boff[4][2];
#pragma unroll
    for (int mi = 0; mi < 8; ++mi) {
        int r = wr * 128 + mi * 16 + (lane & 15);
        int s3 = (r & 7) ^ ((r >> 3) & 7);
#pragma unroll
        for (int kk = 0; kk < 2; ++kk)
            aoff[mi][kk] = r * 64 + ((((lane >> 4) + kk * 4) ^ s3)) * 8;
    }
#pragma unroll
    for (int ni = 0; ni < 4; ++ni) {
        int r = wc * 64 + ni * 16 + (lane & 15);
        int s3 = (r & 7) ^ ((r >> 3) & 7);
#pragma unroll
        for (int kk = 0; kk < 2; ++kk)
            boff[ni][kk] = r * 64 + ((((lane >> 4) + kk * 4) ^ s3)) * 8;
    }

    f32x4 acc[8][4] = {};
    f16x8 aF[8], bF[4];

    B_STAGE(0);
    W0; BAR;

#pragma unroll 1
    for (int i = 0; i < 3; ++i) {
        B_TILE(0, 1, true, false);
        B_TILE(1, 0, true, false);
    }
    B_TILE(0, 1, true, false);
    B_TILE(1, 1, false, true);

#pragma unroll
    for (int mi = 0; mi < 8; ++mi) {
        int m = tm + wr * 128 + mi * 16 + (lane & 15);
#pragma unroll
        for (int ni = 0; ni < 4; ++ni) {
            int n0 = tn + wc * 64 + ni * 16 + (lane >> 4) * 4;
            float4 bv = *(const float4*)(bias + n0);
            f32x4 v = acc[mi][ni];
            v[0] += bv.x; v[1] += bv.y; v[2] += bv.z; v[3] += bv.w;
            *(f32x4*)(O + (size_t)m * 512 + n0) = v;
        }
    }
}

// ---------------- launch ------------------------------------------------------
extern "C" void kernel_launch(void* const* d_in, const int* in_sizes, int n_in,
                              void* d_out, int out_size, void* d_ws, size_t ws_size,
                              hipStream_t stream) {
    const float* x = (const float*)d_in[0];
    const float* wqkv = (const float*)d_in[1];
    const float* wout = (const float*)d_in[2];
    const float* bout = (const float*)d_in[3];
    float* out = (float*)d_out;
    char* ws = (char*)d_ws;
    const size_t MBs = 1u << 20;

    f16* yb  = (f16*)(ws + 0);            // 32MB (was xb; x now read directly)
    f16* wqb = (f16*)(ws + 32 * MBs);     // 1.5MB
    f16* wob = (f16*)(ws + 34 * MBs);     // 0.5MB
    f16* Qb  = (f16*)(ws + 35 * MBs);     // 32MB
    f16* Kb  = (f16*)(ws + 67 * MBs);     // 32MB
    f16* Vb  = (f16*)(ws + 99 * MBs);     // 32MB

    prep_k<<<256, 256, 0, stream>>>(wqkv, wout, wqb, wob);
    g16_k<<<3072, 256, 0, stream>>>(x, wqb, Qb, Kb, Vb);
    attn_k<<<256, 512, 0, stream>>>(Qb, Kb, Vb, yb);
    out_k<<<256, 512, 0, stream>>>(yb, wob, out, bout);
}

// Round 19
// 185.058 us; speedup vs baseline: 1.4782x; 1.4782x over previous
//
#include <hip/hip_runtime.h>
#include <stdint.h>
#include <stddef.h>

typedef _Float16 f16;
typedef _Float16 f16x8 __attribute__((ext_vector_type(8)));
typedef _Float16 f16x4 __attribute__((ext_vector_type(4)));
typedef float f32x4 __attribute__((ext_vector_type(4)));

__device__ __forceinline__ void gload16(const void* g, void* l) {
    auto gp = (const __attribute__((address_space(1))) uint32_t*)(uintptr_t)g;
    auto lp = (__attribute__((address_space(3))) uint32_t*)(uintptr_t)l;
    __builtin_amdgcn_global_load_lds(gp, lp, 16, 0, 0);
}

__device__ __forceinline__ f16x4 cvt4(f32x4 v) {
    return f16x4{ (f16)v[0], (f16)v[1], (f16)v[2], (f16)v[3] };
}

// ---------------- prep: f32 -> f16 conversions --------------------------------
__global__ __launch_bounds__(256) void prep_k(const float* __restrict__ x,
                                              const float* __restrict__ wqkv,
                                              const float* __restrict__ wout,
                                              f16* __restrict__ xb,
                                              f16* __restrict__ wqb,
                                              f16* __restrict__ wob) {
    int tid = blockIdx.x * blockDim.x + threadIdx.x;
    int stride = gridDim.x * blockDim.x;
    for (int i = tid; i < 4194304; i += stride) {
        float4 v = ((const float4*)x)[i];
        *(f16x4*)(xb + (size_t)i * 4) = f16x4{ (f16)v.x, (f16)v.y, (f16)v.z, (f16)v.w };
    }
    for (int i = tid; i < 196608; i += stride) {
        float4 v = ((const float4*)wqkv)[i];
        *(f16x4*)(wqb + (size_t)i * 4) = f16x4{ (f16)v.x, (f16)v.y, (f16)v.z, (f16)v.w };
    }
    for (int i = tid; i < 65536; i += stride) {
        float4 v = ((const float4*)wout)[i];
        *(f16x4*)(wob + (size_t)i * 4) = f16x4{ (f16)v.x, (f16)v.y, (f16)v.z, (f16)v.w };
    }
}

#define W0  asm volatile("s_waitcnt vmcnt(0)" ::: "memory")
#define BAR __builtin_amdgcn_s_barrier()

// ============ ENGINE A2: g15 = merged QKV (r14 verbatim) ======================
#define A_STAGE(NB) do {                                                        \
    gload16(Ab + kb + sE,          &ldsA[NB][( 0 + wid*8)*64]);                 \
    gload16(Ab + kb + sO + 32768,  &ldsA[NB][(32 + wid*8)*64]);                 \
    gload16(Ab + kb + sE + 65536,  &ldsA[NB][(64 + wid*8)*64]);                 \
    gload16(Ab + kb + sO + 98304,  &ldsA[NB][(96 + wid*8)*64]);                 \
    gload16(Bb + kb + sE,          &ldsB[NB][( 0 + wid*8)*64]);                 \
    gload16(Bb + kb + sO + 32768,  &ldsB[NB][(32 + wid*8)*64]);                 \
    gload16(Bb + kb + sE + 65536,  &ldsB[NB][(64 + wid*8)*64]);                 \
    gload16(Bb + kb + sO + 98304,  &ldsB[NB][(96 + wid*8)*64]);                 \
    kb += 128;                                                                  \
} while (0)

#define A_RD(SET, BUF) do {                                                     \
    _Pragma("unroll") for (int mi = 0; mi < 4; ++mi)                            \
    _Pragma("unroll") for (int kk = 0; kk < 2; ++kk)                            \
        aF##SET[mi][kk] = *(const f16x8*)(&ldsA[BUF][0] + aoff[mi][kk]);        \
    _Pragma("unroll") for (int ni = 0; ni < 4; ++ni)                            \
    _Pragma("unroll") for (int kk = 0; kk < 2; ++kk)                            \
        bF##SET[ni][kk] = *(const f16x8*)(&ldsB[BUF][0] + boff[ni][kk]);        \
} while (0)

#define A_MM(SET, KK, ML, MH_) do {                                             \
    __builtin_amdgcn_s_setprio(1);                                              \
    if (qk) {                                                                   \
        _Pragma("unroll") for (int mi = ML; mi < MH_; ++mi)                     \
        _Pragma("unroll") for (int ni = 0; ni < 4; ++ni)                        \
            acc[mi][ni] = __builtin_amdgcn_mfma_f32_16x16x32_f16(               \
                aF##SET[mi][KK], bF##SET[ni][KK], acc[mi][ni], 0, 0, 0);        \
    } else {                                                                    \
        _Pragma("unroll") for (int mi = ML; mi < MH_; ++mi)                     \
        _Pragma("unroll") for (int ni = 0; ni < 4; ++ni)                        \
            acc[mi][ni] = __builtin_amdgcn_mfma_f32_16x16x32_f16(               \
                bF##SET[ni][KK], aF##SET[mi][KK], acc[mi][ni], 0, 0, 0);        \
    }                                                                           \
    __builtin_amdgcn_s_setprio(0);                                              \
} while (0)

#define A_MM3(SET)   do { A_MM(SET, 0, 0, 2); A_MM(SET, 0, 2, 4); A_MM(SET, 1, 0, 2); } while (0)
#define A_MMLAST(SET) A_MM(SET, 1, 2, 4)

#define A_TILE(CUR, NXT, NB, STG, FINAL) do {                                   \
    if (STG) A_STAGE(NB);                                                       \
    A_MM3(CUR);                                                                 \
    if (!FINAL) { W0; BAR; A_RD(NXT, NB); }                                     \
    A_MMLAST(CUR);                                                              \
} while (0)

__global__ __launch_bounds__(256, 2) void g15_k(const f16* __restrict__ A0,
                                                const f16* __restrict__ B0,
                                                f16* __restrict__ Qd,
                                                f16* __restrict__ Kd,
                                                f16* __restrict__ Vd) {
    __shared__ f16 ldsA[2][8192];
    __shared__ f16 ldsB[2][8192];

    const int tid = threadIdx.x;
    const int lane = tid & 63;
    const int wid = tid >> 6;
    const int wr = wid >> 1;
    const int wc = wid & 1;

    const int bid = blockIdx.x;
    const bool qk = bid < 2048;
    int tm, tn;
    if (qk) {
        int swz = (bid & 7) * 256 + (bid >> 3);
        tm = (swz >> 3) * 128; tn = (swz & 7) * 128;
    } else {
        int b2 = bid - 2048;
        int swz = (b2 & 7) * 128 + (b2 >> 3);
        tm = (swz >> 2) * 128; tn = (swz & 3) * 128 + 1024;
    }

    const char* Ab = (const char*)(A0 + (size_t)tm * 512);
    const char* Bb = (const char*)(B0 + (size_t)tn * 512);

    const int u = tid >> 3;
    const int colE = ((tid & 7) ^ ((u & 7) ^ (u >> 3))) * 16;
    const int sE = u * 1024 + colE;
    const int sO = sE ^ 64;
    int kb = 0;

    int aoff[4][2], boff[4][2];
#pragma unroll
    for (int mi = 0; mi < 4; ++mi) {
        int r = qk ? ((lane & 15) * 8 + wr * 4 + mi)
                   : (wr * 64 + mi * 16 + (lane & 15));
#pragma unroll
        for (int kk = 0; kk < 2; ++kk) {
            int c8 = (lane >> 4) + kk * 4;
            aoff[mi][kk] = r * 64 + (c8 ^ ((r & 7) ^ ((r >> 3) & 7))) * 8;
        }
    }
#pragma unroll
    for (int ni = 0; ni < 4; ++ni) {
        int r = wc * 64 + ni * 16 + (lane & 15);
#pragma unroll
        for (int kk = 0; kk < 2; ++kk) {
            int c8 = (lane >> 4) + kk * 4;
            boff[ni][kk] = r * 64 + (c8 ^ ((r & 7) ^ ((r >> 3) & 7))) * 8;
        }
    }

    f32x4 acc[4][4] = {};
    f16x8 aF0[4][2], bF0[4][2], aF1[4][2], bF1[4][2];

    A_STAGE(0);
    W0; BAR;
    A_RD(0, 0);

#pragma unroll 1
    for (int i = 0; i < 3; ++i) {
        A_TILE(0, 1, 1, true, false);
        A_TILE(1, 0, 0, true, false);
    }
    A_TILE(0, 1, 1, true, false);
    A_TILE(1, 1, 1, false, true);

    if (qk) {
        const int b = tm >> 12;
        const int lt = (tm & 4095) >> 3;
        f16* dst = (tn < 512) ? Qd : Kd;
        const int cb = (tn & 511) + wc * 64;
        const int lh0 = lt + (lane >> 4) * 4;
#pragma unroll
        for (int mi = 0; mi < 4; ++mi) {
            int h = wr * 4 + mi;
#pragma unroll
            for (int ni = 0; ni < 4; ++ni) {
                int c = cb + ni * 16 + (lane & 15);
                *(f16x4*)(dst + ((size_t)((b * 8 + h) * 512 + c)) * 512 + lh0) =
                    cvt4(acc[mi][ni]);
            }
        }
    } else {
        f16* dst = Vd;
#pragma unroll
        for (int mi = 0; mi < 4; ++mi) {
            int t = tm + wr * 64 + mi * 16 + (lane & 15);
            int b = t >> 12, l = t & 4095;
            int h = l & 7, lh = l >> 3;
#pragma unroll
            for (int ni = 0; ni < 4; ++ni) {
                int d0 = (tn - 1024) + wc * 64 + ni * 16 + (lane >> 4) * 4;
                *(f16x4*)(dst + ((size_t)((b * 8 + h) * 512 + lh)) * 512 + d0) =
                    cvt4(acc[mi][ni]);
            }
        }
    }
}

// ======= ENGINE F: fused attention (r17 verbatim) =============================
#define F_STAGE(B) do {                                                         \
    gload16(Qt + kb + soff,           &L[65536 + (B)*8192 + ( 0 + wid*8)*64]);  \
    gload16(Qt + kb + soff + 65536,   &L[65536 + (B)*8192 + (64 + wid*8)*64]);  \
    gload16(Kt + kb + soff,           &L[(B)*32768 + (  0 + wid*8)*64]);        \
    gload16(Kt + kb + soff + 65536,   &L[(B)*32768 + ( 64 + wid*8)*64]);        \
    gload16(Kt + kb + soff + 131072,  &L[(B)*32768 + (128 + wid*8)*64]);        \
    gload16(Kt + kb + soff + 196608,  &L[(B)*32768 + (192 + wid*8)*64]);        \
    gload16(Kt + kb + soff + 262144,  &L[(B)*32768 + (256 + wid*8)*64]);        \
    gload16(Kt + kb + soff + 327680,  &L[(B)*32768 + (320 + wid*8)*64]);        \
    gload16(Kt + kb + soff + 393216,  &L[(B)*32768 + (384 + wid*8)*64]);        \
    gload16(Kt + kb + soff + 458752,  &L[(B)*32768 + (448 + wid*8)*64]);        \
    kb += 128;                                                                  \
} while (0)

#define F_RD(KK, B) do {                                                        \
    _Pragma("unroll") for (int ni = 0; ni < 4; ++ni)                            \
        bF[ni] = *(const f16x8*)(&L[(B)*32768] + boff[ni][KK]);                 \
    _Pragma("unroll") for (int mi = 0; mi < 8; ++mi)                            \
        aF[mi] = *(const f16x8*)(&L[65536 + (B)*8192] + aoff[mi][KK]);          \
} while (0)

#define F_MM do {                                                               \
    __builtin_amdgcn_s_setprio(1);                                              \
    _Pragma("unroll") for (int mi = 0; mi < 8; ++mi)                            \
    _Pragma("unroll") for (int ni = 0; ni < 4; ++ni)                            \
        acc[mi][ni] = __builtin_amdgcn_mfma_f32_16x16x32_f16(                   \
            aF[mi], bF[ni], acc[mi][ni], 0, 0, 0);                              \
    __builtin_amdgcn_s_setprio(0);                                              \
} while (0)

__global__ __launch_bounds__(512) void attn_k(const f16* __restrict__ Qb,
                                              const f16* __restrict__ Kb,
                                              const f16* __restrict__ Vb,
                                              f16* __restrict__ yb) {
    __shared__ __align__(16) f16 L[81920];   // 160 KB exactly

    const int tid = threadIdx.x;
    const int lane = tid & 63;
    const int wid = tid >> 6;
    const int g = lane >> 4;
    const int li = lane & 15;

    const int bid = blockIdx.x;
    const int swz = (bid & 7) * 32 + (bid >> 3);
    const int bh = swz >> 2, ct = swz & 3;
    const int b = bh >> 3, h = bh & 7;

    const char* Qt = (const char*)(Qb + (size_t)bh * 262144 + (size_t)ct * 128 * 512);
    const char* Kt = (const char*)(Kb + (size_t)bh * 262144);
    const char* Vt = (const char*)(Vb + (size_t)bh * 262144);

    const int soff = (tid >> 3) * 1024 +
                     ((((lane & 7) ^ (lane >> 3) ^ wid) & 7) * 16);
    int kb = 0;

    int aoff[8][2], boff[4][2];
#pragma unroll
    for (int mi = 0; mi < 8; ++mi) {
        int r = mi * 16 + li;
        int s3 = (r & 7) ^ ((r >> 3) & 7);
#pragma unroll
        for (int kk = 0; kk < 2; ++kk)
            aoff[mi][kk] = r * 64 + (((g + kk * 4) ^ s3)) * 8;
    }
#pragma unroll
    for (int ni = 0; ni < 4; ++ni) {
        int r = wid * 64 + ni * 16 + li;
        int s3 = (r & 7) ^ ((r >> 3) & 7);
#pragma unroll
        for (int kk = 0; kk < 2; ++kk)
            boff[ni][kk] = r * 64 + (((g + kk * 4) ^ s3)) * 8;
    }

    f32x4 acc[8][4] = {};
    f16x8 aF[8], bF[4];

    F_STAGE(0);
#pragma unroll 1
    for (int t = 0; t < 8; ++t) {
        const int cb = t & 1;
        if (t < 7) {
            F_STAGE(cb ^ 1);
            asm volatile("s_waitcnt vmcnt(10)" ::: "memory");
        } else {
            W0;
        }
        BAR;
        F_RD(0, cb);
        F_MM;
        F_RD(1, cb);
        F_MM;
        BAR;
    }

    const int voff = (lane >> 2) * 1024 +
                     ((((lane & 3) ^ ((lane >> 2) & 3) ^ g) & 3) * 16);
    f16x8 vr[4];
#pragma unroll
    for (int i = 0; i < 4; ++i)
        vr[i] = *(const f16x8*)(Vt + (size_t)((wid * 4 + i) * 16) * 1024 + voff);

    float* red  = (float*)&L[65536];
    float* redg = (float*)&L[65536 + 2048];

#pragma unroll
    for (int mi = 0; mi < 8; ++mi)
#pragma unroll
        for (int ni = 0; ni < 4; ++ni) acc[mi][ni] *= 0.125f;

#pragma unroll
    for (int mi = 0; mi < 8; ++mi)
#pragma unroll
        for (int j = 0; j < 4; ++j) {
            float v = fmaxf(fmaxf(acc[mi][0][j], acc[mi][1][j]),
                            fmaxf(acc[mi][2][j], acc[mi][3][j]));
#pragma unroll
            for (int off = 1; off < 16; off <<= 1) v = fmaxf(v, __shfl_xor(v, off, 64));
            if (li == 0) red[wid * 128 + mi * 16 + g * 4 + j] = v;
        }
    BAR;
    if (tid < 128) {
        float m = red[tid];
#pragma unroll
        for (int w = 1; w < 8; ++w) m = fmaxf(m, red[w * 128 + tid]);
        redg[tid] = m;
    }
    BAR;

#pragma unroll
    for (int mi = 0; mi < 8; ++mi)
#pragma unroll
        for (int j = 0; j < 4; ++j) {
            float mg = redg[mi * 16 + g * 4 + j];
            float s = 0.f;
#pragma unroll
            for (int ni = 0; ni < 4; ++ni) {
                float e = __expf(acc[mi][ni][j] - mg);
                acc[mi][ni][j] = e;
                s += e;
            }
#pragma unroll
            for (int off = 1; off < 16; off <<= 1) s += __shfl_xor(s, off, 64);
            if (li == 0) red[wid * 128 + mi * 16 + g * 4 + j] = s;
        }
    BAR;
    if (tid < 128) {
        float s = red[tid];
#pragma unroll
        for (int w = 1; w < 8; ++w) s += red[w * 128 + tid];
        redg[tid] = 1.0f / s;
    }
    BAR;

#pragma unroll
    for (int mi = 0; mi < 8; ++mi)
#pragma unroll
        for (int j = 0; j < 4; ++j) {
            int c = mi * 16 + g * 4 + j;
            int s3c = (c & 7) ^ ((c >> 3) & 7);
            float is = redg[c];
#pragma unroll
            for (int ni = 0; ni < 4; ++ni) {
                int dch = wid * 8 + ni * 2 + (li >> 3);
                L[c * 512 + ((dch ^ s3c) << 3) + (li & 7)] =
                    (f16)(acc[mi][ni][j] * is);
            }
        }
    BAR;

#pragma unroll
    for (int mi = 0; mi < 8; ++mi)
#pragma unroll
        for (int ni = 0; ni < 4; ++ni) acc[mi][ni] = f32x4{0.f, 0.f, 0.f, 0.f};

#pragma unroll 1
    for (int dt = 0; dt < 16; ++dt) {
#pragma unroll
        for (int i = 0; i < 4; ++i)
            *(f16x8*)&L[65536 + (wid * 4 + i) * 512 + lane * 8] = vr[i];
        if (dt < 15) {
#pragma unroll
            for (int i = 0; i < 4; ++i)
                vr[i] = *(const f16x8*)(Vt + (size_t)((wid * 4 + i) * 16) * 1024 +
                                        (dt + 1) * 64 + voff);
        }
        asm volatile("s_waitcnt lgkmcnt(0)" ::: "memory");
        BAR;
        f16x8 aP[8], bV[4];
#pragma unroll
        for (int mi = 0; mi < 8; ++mi) {
            int c = mi * 16 + li;
            int s3c = (c & 7) ^ ((c >> 3) & 7);
            aP[mi] = *(const f16x8*)&L[c * 512 + (((dt * 4 + g) ^ s3c) << 3)];
        }
#pragma unroll
        for (int ni = 0; ni < 4; ++ni) {
            int lr = wid * 64 + ni * 16 + li;
            int s2 = (lr & 3) ^ ((lr >> 2) & 3);
            bV[ni] = *(const f16x8*)&L[65536 + lr * 32 + ((g ^ s2) & 3) * 8];
        }
        __builtin_amdgcn_s_setprio(1);
#pragma unroll
        for (int mi = 0; mi < 8; ++mi)
#pragma unroll
            for (int ni = 0; ni < 4; ++ni)
                acc[mi][ni] = __builtin_amdgcn_mfma_f32_16x16x32_f16(
                    aP[mi], bV[ni], acc[mi][ni], 0, 0, 0);
        __builtin_amdgcn_s_setprio(0);
        BAR;
    }

#pragma unroll
    for (int mi = 0; mi < 8; ++mi) {
        int c0 = ct * 128 + mi * 16 + g * 4;
#pragma unroll
        for (int ni = 0; ni < 4; ++ni) {
            int l = wid * 64 + ni * 16 + li;
            size_t tok = (size_t)b * 4096 + (size_t)l * 8 + h;
            *(f16x4*)(yb + tok * 512 + c0) = cvt4(acc[mi][ni]);
        }
    }
}

// ======================= ENGINE B: out_k (r17 verbatim) =======================
#define B_STAGE(NB) do {                                                        \
    gload16(At + soff,          &ldsA2[NB][(  0 + wid*8)*64]);                  \
    gload16(At + soff + 65536,  &ldsA2[NB][( 64 + wid*8)*64]);                  \
    gload16(At + soff + 131072, &ldsA2[NB][(128 + wid*8)*64]);                  \
    gload16(At + soff + 196608, &ldsA2[NB][(192 + wid*8)*64]);                  \
    gload16(Bt + soff,          &ldsB2[NB][(  0 + wid*8)*64]);                  \
    gload16(Bt + soff + 65536,  &ldsB2[NB][( 64 + wid*8)*64]);                  \
    gload16(Bt + soff + 131072, &ldsB2[NB][(128 + wid*8)*64]);                  \
    gload16(Bt + soff + 196608, &ldsB2[NB][(192 + wid*8)*64]);                  \
    At += 128; Bt += 128;                                                       \
} while (0)

#define B_RD12(KK, BUF) do {                                                    \
    _Pragma("unroll") for (int ni = 0; ni < 4; ++ni)                            \
        bF[ni] = *(const f16x8*)(&ldsB2[BUF][0] + boff[ni][KK]);                \
    _Pragma("unroll") for (int mi = 0; mi < 8; ++mi)                            \
        aF[mi] = *(const f16x8*)(&ldsA2[BUF][0] + aoff[mi][KK]);                \
} while (0)

#define B_MM32 do {                                                             \
    __builtin_amdgcn_s_setprio(1);                                              \
    _Pragma("unroll") for (int mi = 0; mi < 8; ++mi)                            \
    _Pragma("unroll") for (int ni = 0; ni < 4; ++ni)                            \
        acc[mi][ni] = __builtin_amdgcn_mfma_f32_16x16x32_f16(                   \
            bF[ni], aF[mi], acc[mi][ni], 0, 0, 0);                              \
    __builtin_amdgcn_s_setprio(0);                                              \
} while (0)

#define B_TILE(CB, NB, STG, FINAL) do {                                         \
    B_RD12(0, CB);                                                              \
    if (STG) B_STAGE(NB);                                                       \
    B_MM32;                                                                     \
    B_RD12(1, CB);                                                              \
    B_MM32;                                                                     \
    if (!FINAL) { W0; BAR; }                                                    \
} while (0)

__global__ __launch_bounds__(512) void out_k(const f16* __restrict__ A0,
                                             const f16* __restrict__ B0,
                                             float* __restrict__ O,
                                             const float* __restrict__ bias) {
    __shared__ f16 ldsA2[2][16384];
    __shared__ f16 ldsB2[2][16384];

    const int tid = threadIdx.x;
    const int lane = tid & 63;
    const int wid = tid >> 6;
    const int wr = wid >> 2;
    const int wc = wid & 3;

    const int bid = blockIdx.x;
    int swz = (bid & 7) * 32 + (bid >> 3);   // 256 blocks, bijective
    int tm = (swz >> 1) * 256, tn = (swz & 1) * 256;

    const char* At = (const char*)(A0 + (size_t)tm * 512);
    const char* Bt = (const char*)(B0 + (size_t)tn * 512);

    const int soff = wid * 8192 + (lane >> 3) * 1024 +
                     ((((lane & 7) ^ (lane >> 3) ^ wid) & 7) * 16);

    int aoff[8][2], boff[4][2];
#pragma unroll
    for (int mi = 0; mi < 8; ++mi) {
        int r = wr * 128 + mi * 16 + (lane & 15);
        int s3 = (r & 7) ^ ((r >> 3) & 7);
#pragma unroll
        for (int kk = 0; kk < 2; ++kk)
            aoff[mi][kk] = r * 64 + ((((lane >> 4) + kk * 4) ^ s3)) * 8;
    }
#pragma unroll
    for (int ni = 0; ni < 4; ++ni) {
        int r = wc * 64 + ni * 16 + (lane & 15);
        int s3 = (r & 7) ^ ((r >> 3) & 7);
#pragma unroll
        for (int kk = 0; kk < 2; ++kk)
            boff[ni][kk] = r * 64 + ((((lane >> 4) + kk * 4) ^ s3)) * 8;
    }

    f32x4 acc[8][4] = {};
    f16x8 aF[8], bF[4];

    B_STAGE(0);
    W0; BAR;

#pragma unroll 1
    for (int i = 0; i < 3; ++i) {
        B_TILE(0, 1, true, false);
        B_TILE(1, 0, true, false);
    }
    B_TILE(0, 1, true, false);
    B_TILE(1, 1, false, true);

#pragma unroll
    for (int mi = 0; mi < 8; ++mi) {
        int m = tm + wr * 128 + mi * 16 + (lane & 15);
#pragma unroll
        for (int ni = 0; ni < 4; ++ni) {
            int n0 = tn + wc * 64 + ni * 16 + (lane >> 4) * 4;
            float4 bv = *(const float4*)(bias + n0);
            f32x4 v = acc[mi][ni];
            v[0] += bv.x; v[1] += bv.y; v[2] += bv.z; v[3] += bv.w;
            *(f32x4*)(O + (size_t)m * 512 + n0) = v;
        }
    }
}

// ---------------- launch ------------------------------------------------------
extern "C" void kernel_launch(void* const* d_in, const int* in_sizes, int n_in,
                              void* d_out, int out_size, void* d_ws, size_t ws_size,
                              hipStream_t stream) {
    const float* x = (const float*)d_in[0];
    const float* wqkv = (const float*)d_in[1];
    const float* wout = (const float*)d_in[2];
    const float* bout = (const float*)d_in[3];
    float* out = (float*)d_out;
    char* ws = (char*)d_ws;
    const size_t MBs = 1u << 20;

    f16* xb  = (f16*)(ws + 0);            // 32MB
    f16* wqb = (f16*)(ws + 32 * MBs);     // 1.5MB
    f16* wob = (f16*)(ws + 34 * MBs);     // 0.5MB
    f16* Qb  = (f16*)(ws + 35 * MBs);     // 32MB
    f16* Kb  = (f16*)(ws + 67 * MBs);     // 32MB
    f16* Vb  = (f16*)(ws + 99 * MBs);     // 32MB
    f16* yb  = xb;                        // alias: xb dead after QKV GEMM

    prep_k<<<1024, 256, 0, stream>>>(x, wqkv, wout, xb, wqb, wob);
    g15_k<<<3072, 256, 0, stream>>>(xb, wqb, Qb, Kb, Vb);
    attn_k<<<256, 512, 0, stream>>>(Qb, Kb, Vb, yb);
    out_k<<<256, 512, 0, stream>>>(yb, wob, out, bout);
}